// Round 3
// baseline (2533.455 us; speedup 1.0000x reference)
//
#include <hip/hip_runtime.h>
#include <math.h>

// Problem constants (reference: B,T,D=16,512,256; HS=512, D_A=64, R=8)
#define BB 16
#define TT 512
#define DD 256
#define HS 512
#define DA 64
#define RR 8
#define G4H 2048   // 4*HS

// -------- workspace layout (float offsets) --------
// s     :        0  (B*T*R =  65536)  <- k5's hbuf64+xflag overlay this
// e     :    65536
// inv   :   131072
// M     :   196608  (B*T*D   = 2097152)
// gates :  2293760  (B*T*4H  = 16777216)

// ============================================================
// K1: s[b,t,r] = tanh(x[b,t,:] @ w1 + b1) @ w2 + b2
// ============================================================
__global__ __launch_bounds__(256) void k1_score(
    const float* __restrict__ x, const float* __restrict__ w1,
    const float* __restrict__ b1, const float* __restrict__ w2,
    const float* __restrict__ b2, float* __restrict__ s_out) {
  const int wave = threadIdx.x >> 6;
  const int lane = threadIdx.x & 63;
  for (int i = 0; i < 4; ++i) {
    const int bt = blockIdx.x * 16 + wave * 4 + i;  // grid=512 -> 8192 bt
    const float* xr = x + bt * DD;
    float acc = b1[lane];
    #pragma unroll 4
    for (int d = 0; d < DD; ++d)
      acc = fmaf(xr[d], w1[d * DA + lane], acc);   // w1 coalesced over lanes
    const float a = tanhf(acc);
    #pragma unroll
    for (int r = 0; r < RR; ++r) {
      float v = a * w2[lane * RR + r];
      for (int off = 32; off > 0; off >>= 1) v += __shfl_xor(v, off);
      if (lane == 0) s_out[bt * RR + r] = v + b2[r];
    }
  }
}

// ============================================================
// K2: per (b,r): m=max_t s; e=exp(s-m); den=inclusive prefix sum
// ============================================================
__global__ __launch_bounds__(512) void k2_prefix(
    const float* __restrict__ s_in, float* __restrict__ e_out,
    float* __restrict__ inv_out) {
  const int b = blockIdx.x >> 3, r = blockIdx.x & 7;
  const int t = threadIdx.x;
  __shared__ float red[TT];
  __shared__ float buf[2][TT];
  const float v = s_in[(b * TT + t) * RR + r];
  red[t] = v;
  __syncthreads();
  for (int off = 256; off >= 1; off >>= 1) {
    if (t < off) red[t] = fmaxf(red[t], red[t + off]);
    __syncthreads();
  }
  const float m = red[0];
  const float e = expf(v - m);
  int p = 0;
  buf[0][t] = e;
  __syncthreads();
  for (int off = 1; off < TT; off <<= 1) {
    const float add = (t >= off) ? buf[p][t - off] : 0.f;
    buf[1 - p][t] = buf[p][t] + add;
    __syncthreads();
    p ^= 1;
  }
  const float den = buf[p][t];
  e_out[(b * TT + t) * RR + r] = e;
  inv_out[(b * TT + t) * RR + r] = 1.0f / den;
}

// ============================================================
// K3: M[b,t,d] = (1/R) * sum_r inv[t,r] * prefix_j<=t( e[j,r]*x[b,j,d] )
// ============================================================
__global__ __launch_bounds__(64) void k3_mix(
    const float* __restrict__ x, const float* __restrict__ e_in,
    const float* __restrict__ inv_in, float* __restrict__ Mout) {
  const int b = blockIdx.x >> 2;
  const int d = (blockIdx.x & 3) * 64 + threadIdx.x;
  __shared__ __align__(16) float el[TT * RR];
  __shared__ __align__(16) float il[TT * RR];
  for (int i = threadIdx.x * 4; i < TT * RR; i += 64 * 4) {
    *(float4*)&el[i] = *(const float4*)&e_in[b * TT * RR + i];
    *(float4*)&il[i] = *(const float4*)&inv_in[b * TT * RR + i];
  }
  __syncthreads();
  float4 c0 = {0.f, 0.f, 0.f, 0.f}, c1 = {0.f, 0.f, 0.f, 0.f};
  for (int t = 0; t < TT; ++t) {
    const float xv = x[(b * TT + t) * DD + d];
    const float4 e0 = *(const float4*)&el[t * RR];
    const float4 e1 = *(const float4*)&el[t * RR + 4];
    const float4 i0 = *(const float4*)&il[t * RR];
    const float4 i1 = *(const float4*)&il[t * RR + 4];
    c0.x = fmaf(e0.x, xv, c0.x); c0.y = fmaf(e0.y, xv, c0.y);
    c0.z = fmaf(e0.z, xv, c0.z); c0.w = fmaf(e0.w, xv, c0.w);
    c1.x = fmaf(e1.x, xv, c1.x); c1.y = fmaf(e1.y, xv, c1.y);
    c1.z = fmaf(e1.z, xv, c1.z); c1.w = fmaf(e1.w, xv, c1.w);
    float msum = c0.x * i0.x + c0.y * i0.y + c0.z * i0.z + c0.w * i0.w;
    msum += c1.x * i1.x + c1.y * i1.y + c1.z * i1.z + c1.w * i1.w;
    Mout[(b * TT + t) * DD + d] = msum * 0.125f;
  }
}

// ============================================================
// K4: gates = M(8192x256) @ W_ih(256x2048) + bias   (fp32 SGEMM)
// ============================================================
__global__ __launch_bounds__(256) void k4_gemm(
    const float* __restrict__ A, const float* __restrict__ Bw,
    const float* __restrict__ bias, float* __restrict__ C) {
  const int bn = blockIdx.x & 15;
  const int bm = blockIdx.x >> 4;
  const int tid = threadIdx.x;
  const int tx = tid & 15, ty = tid >> 4;
  __shared__ __align__(16) float As[16][132];
  __shared__ __align__(16) float Bs[16][132];
  const int row0 = bm * 128, col0 = bn * 128;

  float acc[2][4][2][4];
  #pragma unroll
  for (int a = 0; a < 2; ++a)
    #pragma unroll
    for (int i = 0; i < 4; ++i)
      #pragma unroll
      for (int q = 0; q < 2; ++q)
        #pragma unroll
        for (int j = 0; j < 4; ++j) acc[a][i][q][j] = 0.f;

  const int arow = tid >> 1, akc = (tid & 1) * 8;
  const int bkr = tid >> 4, bcc = (tid & 15) * 8;

  for (int k0 = 0; k0 < 256; k0 += 16) {
    const float4 a0 = *(const float4*)&A[(row0 + arow) * 256 + k0 + akc];
    const float4 a1 = *(const float4*)&A[(row0 + arow) * 256 + k0 + akc + 4];
    const float4 b0 = *(const float4*)&Bw[(k0 + bkr) * 2048 + col0 + bcc];
    const float4 b1 = *(const float4*)&Bw[(k0 + bkr) * 2048 + col0 + bcc + 4];
    __syncthreads();
    As[akc + 0][arow] = a0.x; As[akc + 1][arow] = a0.y;
    As[akc + 2][arow] = a0.z; As[akc + 3][arow] = a0.w;
    As[akc + 4][arow] = a1.x; As[akc + 5][arow] = a1.y;
    As[akc + 6][arow] = a1.z; As[akc + 7][arow] = a1.w;
    *(float4*)&Bs[bkr][bcc] = b0;
    *(float4*)&Bs[bkr][bcc + 4] = b1;
    __syncthreads();
    #pragma unroll
    for (int kk = 0; kk < 16; ++kk) {
      float av[8], bv[8];
      *(float4*)&av[0] = *(const float4*)&As[kk][ty * 4];
      *(float4*)&av[4] = *(const float4*)&As[kk][64 + ty * 4];
      *(float4*)&bv[0] = *(const float4*)&Bs[kk][tx * 4];
      *(float4*)&bv[4] = *(const float4*)&Bs[kk][64 + tx * 4];
      #pragma unroll
      for (int a = 0; a < 2; ++a)
        #pragma unroll
        for (int i = 0; i < 4; ++i)
          #pragma unroll
          for (int q = 0; q < 2; ++q)
            #pragma unroll
            for (int j = 0; j < 4; ++j)
              acc[a][i][q][j] = fmaf(av[a * 4 + i], bv[q * 4 + j], acc[a][i][q][j]);
    }
  }
  const float4 bias0 = *(const float4*)&bias[col0 + tx * 4];
  const float4 bias1 = *(const float4*)&bias[col0 + 64 + tx * 4];
  #pragma unroll
  for (int a = 0; a < 2; ++a)
    #pragma unroll
    for (int i = 0; i < 4; ++i) {
      const int row = row0 + a * 64 + ty * 4 + i;
      float4 v0, v1;
      v0.x = acc[a][i][0][0] + bias0.x; v0.y = acc[a][i][0][1] + bias0.y;
      v0.z = acc[a][i][0][2] + bias0.z; v0.w = acc[a][i][0][3] + bias0.w;
      v1.x = acc[a][i][1][0] + bias1.x; v1.y = acc[a][i][1][1] + bias1.y;
      v1.z = acc[a][i][1][2] + bias1.z; v1.w = acc[a][i][1][3] + bias1.w;
      *(float4*)&C[row * 2048 + col0 + tx * 4] = v0;
      *(float4*)&C[row * 2048 + col0 + 64 + tx * 4] = v1;
    }
}

#define FMA4(ACC, W4, HSC)                         \
  ACC.x = fmaf((W4).x, (HSC), ACC.x);              \
  ACC.y = fmaf((W4).y, (HSC), ACC.y);              \
  ACC.z = fmaf((W4).z, (HSC), ACC.z);              \
  ACC.w = fmaf((W4).w, (HSC), ACC.w);

// fast transcendentals: v_exp_f32 + v_rcp_f32 (~1e-6 err << 1.5e-2 tol)
__device__ __forceinline__ float fast_sigmoid(float x) {
  return __builtin_amdgcn_rcpf(1.f + __expf(-x));
}
__device__ __forceinline__ float fast_tanh(float x) {
  const float xc = fmaxf(x, -30.f);           // avoid inf*0 NaN
  const float e = __expf(-2.f * xc);
  return (1.f - e) * __builtin_amdgcn_rcpf(1.f + e);
}

#define HPOLL(Q) __hip_atomic_load((Q), __ATOMIC_RELAXED, __HIP_MEMORY_SCOPE_AGENT)

// sc0 load: bypass L1, read at the XCD-shared L2. Single dwordx2 (no tear).
__device__ __forceinline__ unsigned long long poll_sc0(
    const unsigned long long* p) {
  unsigned long long v;
  asm volatile("global_load_dwordx2 %0, %1, off sc0\n\ts_waitcnt vmcnt(0)"
               : "=v"(v) : "v"(p));
  return v;
}
// sc0 store: write-through so the packet is visible at the shared L2
// (a PLAIN store may sit dirty in a write-back L1 forever -- the
// suspected v9 hang). Single dwordx2.
__device__ __forceinline__ void store_sc0(unsigned long long* p,
                                          unsigned long long v) {
  asm volatile("global_store_dwordx2 %0, %1, off sc0"
               :: "v"(p), "v"(v) : "memory");
}

// ============================================================
// K5 v10: v7 protocol (899us, proven) + HANG-PROOF XCD-local fast path.
// R2 post-mortem: v9 hung (harness timeout). Suspected mechanism: fast
// path used a PLAIN producer store + unbounded sc0 consumer poll; if
// CDNA4's L1 is write-back, the store sits dirty in the producer's L1
// (line re-written every 2 steps, never evicted) and the L2-level poll
// never observes it -> spin forever. Two design errors fixed here, sound
// under EVERY cache behavior:
//  (1) producer DUAL-PUBLISH: sc0 store (write-through -> shared L2)
//      then the v7-proven agent atomic store (-> MALL). Same 8B
//      self-validating packet on both paths; any reader is correct.
//  (2) consumer BOUNDED sc0 spin (8) -> fall back to the proven agent
//      poll; permanent per-thread demotion only after warm-up (t>=8)
//      so launch/staging skew can't demote the steady state.
//  (3) XCD-colocation check poll also bounded (4096 -> not-colocated
//      -> pure v7 path). Nothing can spin unbounded unless v7 could.
// Mapping: b=blockIdx&15, s=blockIdx>>4 -> round-robin dispatch puts
// all 16 blocks of batch b on XCD b%8 (verified at runtime, G16).
// Outcome regimes: win ~500-680us k5; mapping-wrong ~= v7; stale-L2
// ~1050us k5 (bounded, passes) -- all three terminate + inform.
// ============================================================
__global__ __launch_bounds__(512, 1) void k5_lstm(
    const float* __restrict__ gates, const float* __restrict__ whh,
    float* __restrict__ out, unsigned long long* hbuf,
    unsigned long long* xflag) {
  const int b   = blockIdx.x & 15;       // batch = sync domain (colocated)
  const int s   = blockIdx.x >> 4;       // unit-slice
  const int tid = threadIdx.x;           // 512 threads
  const int kq  = tid & 15;              // k-chunk: k in [kq*32, kq*32+32)
  const int cq  = tid >> 4;              // unit offset 0..31
  const int j0  = s * 32;
  const int unit = j0 + cq;

  __shared__ __align__(16) float Wl[256 * 128];  // staging, 128 KB
  __shared__ __align__(16) float hl[2][576];     // parity; chunk*36+pos
  __shared__ int sflags[16];
  __shared__ int s_same;

  // ---- XCD-colocation check (agent-scope, BOUNDED; ~1 RT once) ----
  unsigned xcd;
  asm volatile("s_getreg_b32 %0, hwreg(HW_REG_XCC_ID)" : "=s"(xcd));
  if (tid == 0) {
    const unsigned long long mypkt = (1ULL << 32) | (unsigned long long)xcd;
    __hip_atomic_store(&xflag[b * 16 + s], mypkt, __ATOMIC_RELAXED,
                       __HIP_MEMORY_SCOPE_AGENT);
  }
  if (tid < 16) {
    unsigned long long v = 0; int sp = 0;
    do {
      v = HPOLL(&xflag[b * 16 + tid]);
      if (++sp > 4096) break;                      // bounded: never hang
    } while ((unsigned)(v >> 32) == 0u);
    sflags[tid] =
        ((unsigned)(v >> 32) != 0u && (unsigned)v == xcd) ? 1 : 0;
  }
  __syncthreads();
  if (tid == 0) {
    int a = 1;
    for (int i = 0; i < 16; ++i) a &= sflags[i];
    s_same = a;
  }

  // ---- stage W slice (coalesced) and gather into registers ----
  // wr[kk] = (W[k][i-col], W[k][f-col], W[k][g-col], W[k][o-col]) of
  // THIS thread's unit, k = (kq&7)*32 + kk + 256*(kq>>3)-round.
  float4 wr[32];
  for (int rnd = 0; rnd < 2; ++rnd) {
    for (int i = tid * 4; i < 256 * 128; i += 512 * 4) {
      const int k = i >> 7, c = i & 127;   // Wl[k][c], c = gate*32 + uo
      *(float4*)&Wl[i] =
          *(const float4*)&whh[(rnd * 256 + k) * G4H + (c >> 5) * HS + j0 + (c & 31)];
    }
    __syncthreads();
    if ((kq >> 3) == rnd) {
      const int kb = (kq & 7) * 32;
      #pragma unroll
      for (int kk = 0; kk < 32; ++kk) {
        const int base = (kb + kk) * 128 + cq;
        wr[kk].x = *(volatile const float*)&Wl[base];
        wr[kk].y = *(volatile const float*)&Wl[base + 32];
        wr[kk].z = *(volatile const float*)&Wl[base + 64];
        wr[kk].w = *(volatile const float*)&Wl[base + 96];
      }
    }
    __syncthreads();
  }
  bool fast_thr = (s_same != 0);   // per-thread; may demote after warm-up

  float c_reg = 0.f;   // cell state (lives in lanes kq==0; unit j0+cq)

  for (int t = 0; t < TT; ++t) {
    // gate-x prefetch: 4 dwords (i,f,g,o of my unit), in flight over poll
    float gi = 0.f, gf = 0.f, gg = 0.f, go = 0.f;
    if (kq == 0) {
      const float* gt = gates + ((long)b * TT + t) * G4H + unit;
      gi = gt[0]; gf = gt[HS]; gg = gt[2 * HS]; go = gt[3 * HS];
    }
    const int par = t & 1;
    if (t > 0) {
      // self-validating poll of my own unit's packet (tag >= t).
      const unsigned long long* hsrc =
          hbuf + (((t - 1) & 1) * BB + b) * HS + tid;
      const unsigned tt = (unsigned)t;
      unsigned long long pkt;
      if (fast_thr) {
        int spins = 0; bool ok = false;
        for (;;) {
          pkt = poll_sc0(hsrc);
          if ((unsigned)(pkt >> 32) >= tt) { ok = true; break; }
          if (++spins == 8) break;               // bounded: never hang
        }
        if (!ok) {
          if (t >= 8) fast_thr = false;          // steady-state stale: demote
          do { pkt = HPOLL(hsrc); } while ((unsigned)(pkt >> 32) < tt);
        }
      } else {
        do { pkt = HPOLL(hsrc); } while ((unsigned)(pkt >> 32) < tt);
      }
      hl[par][(tid >> 5) * 36 + (tid & 31)] = __uint_as_float((unsigned)pkt);
    }
    __syncthreads();  // the ONE barrier: hl[par] complete
    float4 acc = {0.f, 0.f, 0.f, 0.f};
    if (t > 0) {
      const float* hb = &hl[par][kq * 36];
      #pragma unroll
      for (int i = 0; i < 8; ++i) {
        const float4 h4 = *(const float4*)(hb + i * 4);
        FMA4(acc, wr[i * 4 + 0], h4.x);
        FMA4(acc, wr[i * 4 + 1], h4.y);
        FMA4(acc, wr[i * 4 + 2], h4.z);
        FMA4(acc, wr[i * 4 + 3], h4.w);
      }
    }
    // butterfly over the 16 kq lanes (in-wave: group = 16 consecutive)
    #pragma unroll
    for (int off = 1; off <= 8; off <<= 1) {
      acc.x += __shfl_xor(acc.x, off); acc.y += __shfl_xor(acc.y, off);
      acc.z += __shfl_xor(acc.z, off); acc.w += __shfl_xor(acc.w, off);
    }
    // fused epilogue + publish: lane kq==0 has full (i,f,g,o) of unit
    if (kq == 0) {
      const float I = fast_sigmoid(acc.x + gi);
      const float F = fast_sigmoid(acc.y + gf);
      const float G = fast_tanh(acc.z + gg);
      const float O = fast_sigmoid(acc.w + go);
      c_reg = F * c_reg + I * G;
      const float h = O * fast_tanh(c_reg);
      const unsigned long long pkt =
          ((unsigned long long)(unsigned)(t + 1) << 32) |
          (unsigned long long)__float_as_uint(h);
      unsigned long long* dst = &hbuf[((t & 1) * BB + b) * HS + unit];
      // DUAL publish: sc0 (shared-L2, fast consumers) then agent (MALL,
      // the v7-proven guaranteed path). Identical packet -> any mix of
      // reader paths is correct.
      store_sc0(dst, pkt);
      __hip_atomic_store(dst, pkt, __ATOMIC_RELAXED,
                         __HIP_MEMORY_SCOPE_AGENT);
      out[((long)b * TT + t) * HS + unit] = h;   // hidden_seq (post-publish)
      if (t == TT - 1) {
        out[(long)BB * TT * HS + b * HS + unit] = h;               // h_t
        out[(long)BB * TT * HS + BB * HS + b * HS + unit] = c_reg; // c_t
      }
    }
  }
}

// ============================================================
extern "C" void kernel_launch(void* const* d_in, const int* in_sizes, int n_in,
                              void* d_out, int out_size, void* d_ws,
                              size_t ws_size, hipStream_t stream) {
  const float* x    = (const float*)d_in[0];
  const float* w1   = (const float*)d_in[1];
  const float* b1   = (const float*)d_in[2];
  const float* w2   = (const float*)d_in[3];
  const float* b2   = (const float*)d_in[4];
  const float* wih  = (const float*)d_in[5];
  const float* whh  = (const float*)d_in[6];
  const float* bias = (const float*)d_in[7];
  float* out = (float*)d_out;

  float* ws = (float*)d_ws;
  float* s_buf  = ws;                    // 65536 floats; dead after k2
  float* e_buf  = ws + 65536;
  float* i_buf  = ws + 131072;
  float* M_buf  = ws + 196608;
  float* g_buf  = ws + 2293760;
  // hbuf64 (2*16*512 u64 = 128KB) + xflag (256 u64 = 2KB) overlay the
  // s region (256KB); s is dead by k4.
  unsigned long long* hbuf64 = (unsigned long long*)ws;
  unsigned long long* xflag  = hbuf64 + 2 * BB * HS;

  k1_score<<<512, 256, 0, stream>>>(x, w1, b1, w2, b2, s_buf);
  k2_prefix<<<BB * RR, 512, 0, stream>>>(s_buf, e_buf, i_buf);
  k3_mix<<<64, 64, 0, stream>>>(x, e_buf, i_buf, M_buf);
  k4_gemm<<<64 * 16, 256, 0, stream>>>(M_buf, wih, bias, g_buf);
  // zero packet tags + xcd flags (ws re-poisoned 0xAA each call;
  // 0xAAAAAAAA > any t would instantly satisfy polls). Stream-ordered
  // after k2's s_buf reads.
  hipMemsetAsync(hbuf64, 0,
                 (2 * BB * HS + 256) * sizeof(unsigned long long), stream);
  k5_lstm<<<256, 512, 0, stream>>>(g_buf, whh, out, hbuf64, xflag);
}

// Round 4
// 1061.074 us; speedup vs baseline: 2.3876x; 2.3876x over previous
//
#include <hip/hip_runtime.h>
#include <math.h>

// Problem constants (reference: B,T,D=16,512,256; HS=512, D_A=64, R=8)
#define BB 16
#define TT 512
#define DD 256
#define HS 512
#define DA 64
#define RR 8
#define G4H 2048   // 4*HS

// -------- workspace layout (float offsets) --------
// s     :        0  (B*T*R =  65536)  <- k5's hbuf64 overlays this (dead by k3)
// e     :    65536
// inv   :   131072
// M     :   196608  (B*T*D   = 2097152)
// (gates buffer no longer needed: k4 fused into k5)

// ============================================================
// K1: s[b,t,r] = tanh(x[b,t,:] @ w1 + b1) @ w2 + b2
// ============================================================
__global__ __launch_bounds__(256) void k1_score(
    const float* __restrict__ x, const float* __restrict__ w1,
    const float* __restrict__ b1, const float* __restrict__ w2,
    const float* __restrict__ b2, float* __restrict__ s_out) {
  const int wave = threadIdx.x >> 6;
  const int lane = threadIdx.x & 63;
  for (int i = 0; i < 4; ++i) {
    const int bt = blockIdx.x * 16 + wave * 4 + i;  // grid=512 -> 8192 bt
    const float* xr = x + bt * DD;
    float acc = b1[lane];
    #pragma unroll 4
    for (int d = 0; d < DD; ++d)
      acc = fmaf(xr[d], w1[d * DA + lane], acc);   // w1 coalesced over lanes
    const float a = tanhf(acc);
    #pragma unroll
    for (int r = 0; r < RR; ++r) {
      float v = a * w2[lane * RR + r];
      for (int off = 32; off > 0; off >>= 1) v += __shfl_xor(v, off);
      if (lane == 0) s_out[bt * RR + r] = v + b2[r];
    }
  }
}

// ============================================================
// K2: per (b,r): m=max_t s; e=exp(s-m); den=inclusive prefix sum
// ============================================================
__global__ __launch_bounds__(512) void k2_prefix(
    const float* __restrict__ s_in, float* __restrict__ e_out,
    float* __restrict__ inv_out) {
  const int b = blockIdx.x >> 3, r = blockIdx.x & 7;
  const int t = threadIdx.x;
  __shared__ float red[TT];
  __shared__ float buf[2][TT];
  const float v = s_in[(b * TT + t) * RR + r];
  red[t] = v;
  __syncthreads();
  for (int off = 256; off >= 1; off >>= 1) {
    if (t < off) red[t] = fmaxf(red[t], red[t + off]);
    __syncthreads();
  }
  const float m = red[0];
  const float e = expf(v - m);
  int p = 0;
  buf[0][t] = e;
  __syncthreads();
  for (int off = 1; off < TT; off <<= 1) {
    const float add = (t >= off) ? buf[p][t - off] : 0.f;
    buf[1 - p][t] = buf[p][t] + add;
    __syncthreads();
    p ^= 1;
  }
  const float den = buf[p][t];
  e_out[(b * TT + t) * RR + r] = e;
  inv_out[(b * TT + t) * RR + r] = 1.0f / den;
}

// ============================================================
// K3: M[b,t,d] = (1/R) * sum_r inv[t,r] * prefix_j<=t( e[j,r]*x[b,j,d] )
// ============================================================
__global__ __launch_bounds__(64) void k3_mix(
    const float* __restrict__ x, const float* __restrict__ e_in,
    const float* __restrict__ inv_in, float* __restrict__ Mout) {
  const int b = blockIdx.x >> 2;
  const int d = (blockIdx.x & 3) * 64 + threadIdx.x;
  __shared__ __align__(16) float el[TT * RR];
  __shared__ __align__(16) float il[TT * RR];
  for (int i = threadIdx.x * 4; i < TT * RR; i += 64 * 4) {
    *(float4*)&el[i] = *(const float4*)&e_in[b * TT * RR + i];
    *(float4*)&il[i] = *(const float4*)&inv_in[b * TT * RR + i];
  }
  __syncthreads();
  float4 c0 = {0.f, 0.f, 0.f, 0.f}, c1 = {0.f, 0.f, 0.f, 0.f};
  for (int t = 0; t < TT; ++t) {
    const float xv = x[(b * TT + t) * DD + d];
    const float4 e0 = *(const float4*)&el[t * RR];
    const float4 e1 = *(const float4*)&el[t * RR + 4];
    const float4 i0 = *(const float4*)&il[t * RR];
    const float4 i1 = *(const float4*)&il[t * RR + 4];
    c0.x = fmaf(e0.x, xv, c0.x); c0.y = fmaf(e0.y, xv, c0.y);
    c0.z = fmaf(e0.z, xv, c0.z); c0.w = fmaf(e0.w, xv, c0.w);
    c1.x = fmaf(e1.x, xv, c1.x); c1.y = fmaf(e1.y, xv, c1.y);
    c1.z = fmaf(e1.z, xv, c1.z); c1.w = fmaf(e1.w, xv, c1.w);
    float msum = c0.x * i0.x + c0.y * i0.y + c0.z * i0.z + c0.w * i0.w;
    msum += c1.x * i1.x + c1.y * i1.y + c1.z * i1.z + c1.w * i1.w;
    Mout[(b * TT + t) * DD + d] = msum * 0.125f;
  }
}

#define FMA4(ACC, W4, HSC)                         \
  ACC.x = fmaf((W4).x, (HSC), ACC.x);              \
  ACC.y = fmaf((W4).y, (HSC), ACC.y);              \
  ACC.z = fmaf((W4).z, (HSC), ACC.z);              \
  ACC.w = fmaf((W4).w, (HSC), ACC.w);

// fast transcendentals: v_exp_f32 + v_rcp_f32 (~1e-6 err << 1.5e-2 tol)
__device__ __forceinline__ float fast_sigmoid(float x) {
  return __builtin_amdgcn_rcpf(1.f + __expf(-x));
}
__device__ __forceinline__ float fast_tanh(float x) {
  const float xc = fmaxf(x, -30.f);           // avoid inf*0 NaN
  const float e = __expf(-2.f * xc);
  return (1.f - e) * __builtin_amdgcn_rcpf(1.f + e);
}

#define HPOLL(Q) __hip_atomic_load((Q), __ATOMIC_RELAXED, __HIP_MEMORY_SCOPE_AGENT)

// ============================================================
// K5 v11: v7 exchange protocol EXACTLY (899us proven; R2/R3 sc0 cache-
// scope experiments reverted -- consumer-L2 stale-line spin made them
// 2.4x slower) + K4 FUSED IN.
// Rationale: k5 idles ~2850 of 4214 cyc/step waiting on the MALL-scope
// h-exchange. gates = M @ W_ih + bias is INDEPENDENT of h, so each
// block computes its own units' x-gates inside that idle window:
//  - W_ih slice (256x128 = 128KB) lives in LDS, reusing Wl (dead after
//    the wr gather). Layout [kq][dim][cq] with gates contiguous
//    (float4 b128 reads) and kq-stride padded to 2052 words -> only
//    2-way bank aliasing (free, m136).
//  - M row double-buffered in LDS (stride-20 pad), prefetched 1 step
//    ahead; row t+1's global load is issued at step-t top (full step
//    to land), written to the par^1 buffer just before the barrier.
//  - Thread (kq,cq) seeds acc with the W_ih partial over dims
//    [16kq,16kq+16); the existing kq-butterfly sums it with the U.h
//    partials. bias added in the epilogue lane. Removes k4 entirely
//    plus k5's 67MB of scattered gate loads.
// An empty asm pins acc after the FMA-x so the scheduler cannot sink
// the (poll-independent) FMA-x past the poll loop onto the serial
// chain.
// ============================================================
__global__ __launch_bounds__(512, 1) void k5_lstm(
    const float* __restrict__ Mrow, const float* __restrict__ whh,
    const float* __restrict__ wih, const float* __restrict__ bias,
    float* __restrict__ out, unsigned long long* hbuf) {
  const int s   = blockIdx.x & 15;       // unit-slice
  const int b   = blockIdx.x >> 4;       // batch = sync domain
  const int tid = threadIdx.x;           // 512 threads
  const int kq  = tid & 15;              // k-chunk: k in [kq*32, kq*32+32)
  const int cq  = tid >> 4;              // unit offset 0..31
  const int j0  = s * 32;
  const int unit = j0 + cq;

  __shared__ __align__(16) float Wl[16 * 2052];   // 131328 B (staging + W_ih)
  __shared__ __align__(16) float hl[2][576];      // parity; chunk*36+pos
  __shared__ __align__(16) float M_lds[2][320];   // stride-20 per 16 dims

  // ---- rounds 0-1: stage whh slice, gather wr into registers (= v7) ----
  // wr[kk] = (W[k][i-col], W[k][f-col], W[k][g-col], W[k][o-col]) of
  // THIS thread's unit, k = (kq&7)*32 + kk + 256*(kq>>3)-round.
  float4 wr[32];
  for (int rnd = 0; rnd < 2; ++rnd) {
    for (int i = tid * 4; i < 256 * 128; i += 512 * 4) {
      const int k = i >> 7, c = i & 127;   // Wl[k][c], c = gate*32 + uo
      *(float4*)&Wl[i] =
          *(const float4*)&whh[(rnd * 256 + k) * G4H + (c >> 5) * HS + j0 + (c & 31)];
    }
    __syncthreads();
    if ((kq >> 3) == rnd) {
      const int kb = (kq & 7) * 32;
      #pragma unroll
      for (int kk = 0; kk < 32; ++kk) {
        const int base = (kb + kk) * 128 + cq;
        wr[kk].x = *(volatile const float*)&Wl[base];
        wr[kk].y = *(volatile const float*)&Wl[base + 32];
        wr[kk].z = *(volatile const float*)&Wl[base + 64];
        wr[kk].w = *(volatile const float*)&Wl[base + 96];
      }
    }
    __syncthreads();
  }

  // ---- round 2: stage W_ih slice into Wl, gather-friendly layout ----
  // word(kq,i,cq) = kq*2052 + i*128 + cq*4, float4 = 4 gate columns of
  // unit j0+cq at input-dim kq*16+i. Scalar global loads (stride HS
  // between gates) -- one-time cost, coalesced within gate groups.
  for (int m = tid * 4; m < 32768; m += 2048) {
    const int g_kq = m >> 11, g_i = (m >> 7) & 15, g_cq = (m >> 2) & 31;
    const int row = g_kq * 16 + g_i;
    float4 w4;
    w4.x = wih[row * G4H + 0 * HS + j0 + g_cq];
    w4.y = wih[row * G4H + 1 * HS + j0 + g_cq];
    w4.z = wih[row * G4H + 2 * HS + j0 + g_cq];
    w4.w = wih[row * G4H + 3 * HS + j0 + g_cq];
    *(float4*)&Wl[g_kq * 2052 + g_i * 128 + g_cq * 4] = w4;
  }
  // M row 0 into parity buffer 0 (dim d lives at word (d>>4)*20 + (d&15))
  if (tid < 64)
    *(float4*)&M_lds[0][(tid >> 2) * 20 + (tid & 3) * 4] =
        *(const float4*)&Mrow[(long)b * TT * DD + tid * 4];
  // bias preload (epilogue lanes only)
  float bi = 0.f, bf = 0.f, bg = 0.f, bo = 0.f;
  if (kq == 0) {
    bi = bias[unit];          bf = bias[HS + unit];
    bg = bias[2 * HS + unit]; bo = bias[3 * HS + unit];
  }
  __syncthreads();

  float c_reg = 0.f;   // cell state (lives in lanes kq==0; unit j0+cq)

  for (int t = 0; t < TT; ++t) {
    const int par = t & 1;
    // prefetch M row t+1 (64 threads, one float4 each; lands during step)
    float4 mnext = {0.f, 0.f, 0.f, 0.f};
    if (tid < 64) {
      const int tn = (t + 1 < TT) ? t + 1 : t;   // clamp (last write unused)
      mnext = *(const float4*)&Mrow[((long)b * TT + tn) * DD + tid * 4];
    }
    // FMA-x: acc = W_ih partial over input dims [kq*16, kq*16+16).
    // Independent of h -> sits parallel to the poll in the dep graph.
    float4 acc = {0.f, 0.f, 0.f, 0.f};
    {
      const float* Lp = &Wl[kq * 2052 + cq * 4];
      const float* mp = &M_lds[par][kq * 20];
      #pragma unroll
      for (int i = 0; i < 16; ++i) {
        const float4 w4 = *(const float4*)(Lp + i * 128);
        const float mv = mp[i];
        FMA4(acc, w4, mv);
      }
    }
    // pin: keep FMA-x scheduled before the poll loop (cheap, once/step)
    asm volatile("" : "+v"(acc.x), "+v"(acc.y), "+v"(acc.z), "+v"(acc.w));
    if (t > 0) {
      // self-validating poll of my own unit's packet (tag >= t) -- v7
      const unsigned long long* hsrc =
          hbuf + (((t - 1) & 1) * BB + b) * HS + tid;
      unsigned long long pkt;
      do { pkt = HPOLL(hsrc); } while ((unsigned)(pkt >> 32) < (unsigned)t);
      hl[par][(tid >> 5) * 36 + (tid & 31)] = __uint_as_float((unsigned)pkt);
    }
    // publish M row t+1 for next step (readers are past the barrier)
    if (tid < 64)
      *(float4*)&M_lds[par ^ 1][(tid >> 2) * 20 + (tid & 3) * 4] = mnext;
    __syncthreads();  // the ONE barrier: hl[par] + M_lds[par^1] complete
    if (t > 0) {
      const float* hb = &hl[par][kq * 36];
      #pragma unroll
      for (int i = 0; i < 8; ++i) {
        const float4 h4 = *(const float4*)(hb + i * 4);
        FMA4(acc, wr[i * 4 + 0], h4.x);
        FMA4(acc, wr[i * 4 + 1], h4.y);
        FMA4(acc, wr[i * 4 + 2], h4.z);
        FMA4(acc, wr[i * 4 + 3], h4.w);
      }
    }
    // butterfly over the 16 kq lanes (in-wave: group = 16 consecutive)
    #pragma unroll
    for (int off = 1; off <= 8; off <<= 1) {
      acc.x += __shfl_xor(acc.x, off); acc.y += __shfl_xor(acc.y, off);
      acc.z += __shfl_xor(acc.z, off); acc.w += __shfl_xor(acc.w, off);
    }
    // fused epilogue + publish: lane kq==0 has full (i,f,g,o) of unit
    if (kq == 0) {
      const float I = fast_sigmoid(acc.x + bi);
      const float F = fast_sigmoid(acc.y + bf);
      const float G = fast_tanh(acc.z + bg);
      const float O = fast_sigmoid(acc.w + bo);
      c_reg = F * c_reg + I * G;
      const float h = O * fast_tanh(c_reg);
      const unsigned long long pkt =
          ((unsigned long long)(unsigned)(t + 1) << 32) |
          (unsigned long long)__float_as_uint(h);
      __hip_atomic_store(&hbuf[((t & 1) * BB + b) * HS + unit], pkt,
                         __ATOMIC_RELAXED, __HIP_MEMORY_SCOPE_AGENT);
      out[((long)b * TT + t) * HS + unit] = h;   // hidden_seq (post-publish)
      if (t == TT - 1) {
        out[(long)BB * TT * HS + b * HS + unit] = h;               // h_t
        out[(long)BB * TT * HS + BB * HS + b * HS + unit] = c_reg; // c_t
      }
    }
  }
}

// ============================================================
extern "C" void kernel_launch(void* const* d_in, const int* in_sizes, int n_in,
                              void* d_out, int out_size, void* d_ws,
                              size_t ws_size, hipStream_t stream) {
  const float* x    = (const float*)d_in[0];
  const float* w1   = (const float*)d_in[1];
  const float* b1   = (const float*)d_in[2];
  const float* w2   = (const float*)d_in[3];
  const float* b2   = (const float*)d_in[4];
  const float* wih  = (const float*)d_in[5];
  const float* whh  = (const float*)d_in[6];
  const float* bias = (const float*)d_in[7];
  float* out = (float*)d_out;

  float* ws = (float*)d_ws;
  float* s_buf  = ws;                    // 65536 floats; dead after k2
  float* e_buf  = ws + 65536;
  float* i_buf  = ws + 131072;
  float* M_buf  = ws + 196608;
  // hbuf64 overlays the s region (2*16*512 uint64 = 128 KB <= 256 KB)
  unsigned long long* hbuf64 = (unsigned long long*)ws;

  k1_score<<<512, 256, 0, stream>>>(x, w1, b1, w2, b2, s_buf);
  k2_prefix<<<BB * RR, 512, 0, stream>>>(s_buf, e_buf, i_buf);
  k3_mix<<<64, 64, 0, stream>>>(x, e_buf, i_buf, M_buf);
  // zero the packet tags (ws re-poisoned 0xAA each call; 0xAAAAAAAA > any t
  // would instantly satisfy polls). Stream-ordered after k2's s_buf reads.
  hipMemsetAsync(hbuf64, 0, 2 * BB * HS * sizeof(unsigned long long), stream);
  k5_lstm<<<256, 512, 0, stream>>>(M_buf, whh, wih, bias, out, hbuf64);
}